// Round 2
// baseline (210.806 us; speedup 1.0000x reference)
//
#include <hip/hip_runtime.h>
#include <hip/hip_bf16.h>

#define B_ 4
#define N_ 2048
#define M_ 2048
#define C_ 256
#define H_ 8
#define DH_ 32
#define R_ 128

typedef __bf16 bf16x8 __attribute__((ext_vector_type(8)));
typedef float f32x4 __attribute__((ext_vector_type(4)));

// ---------------- Kernel 0: W^T (f32 -> bf16) for Wq, Wk, Wv ----------------
__global__ __launch_bounds__(256) void wtrans_kernel(
    const float* __restrict__ Wq, const float* __restrict__ Wk,
    const float* __restrict__ Wv, __bf16* __restrict__ out)
{
    __shared__ float t[32][33];
    int pz = blockIdx.z;
    const float* W = pz == 0 ? Wq : (pz == 1 ? Wk : Wv);
    int j0 = blockIdx.x * 32, k0 = blockIdx.y * 32;
    int tx = threadIdx.x, ty = threadIdx.y;
#pragma unroll
    for (int i = 0; i < 4; ++i)
        t[ty + 8 * i][tx] = W[(k0 + ty + 8 * i) * C_ + j0 + tx];
    __syncthreads();
    __bf16* o = out + (size_t)pz * C_ * C_;
#pragma unroll
    for (int i = 0; i < 4; ++i)
        o[(j0 + ty + 8 * i) * C_ + k0 + tx] = (__bf16)t[tx][ty + 8 * i];
}

// ---------------- Kernel 1: projections X@W+b -> bf16, head layouts ----------
// Full 256-col tile per block (X read once). pz=0: q (B,H,N,Dh); pz=1: k; pz=2: v^T (B,H,Dh,M)
__global__ __launch_bounds__(256) void proj_kernel(
    const float* __restrict__ Xq, const float* __restrict__ Xk, const float* __restrict__ Xv,
    const float* __restrict__ bq, const float* __restrict__ bk, const float* __restrict__ bv,
    const __bf16* __restrict__ Wt,
    __bf16* __restrict__ qb, __bf16* __restrict__ kb, __bf16* __restrict__ vt)
{
    int pz = blockIdx.z;
    const float* X = pz == 0 ? Xq : (pz == 1 ? Xk : Xv);
    const float* bias = pz == 0 ? bq : (pz == 1 ? bk : bv);
    const __bf16* W = Wt + (size_t)pz * C_ * C_;

    int r0 = blockIdx.x * 64;
    int w = threadIdx.x >> 6, lane = threadIdx.x & 63;
    int lg = lane >> 4, lr = lane & 15;
    int rw = r0 + w * 16;

    f32x4 z = {0.f, 0.f, 0.f, 0.f};
    f32x4 acc[16];
#pragma unroll
    for (int ns = 0; ns < 16; ++ns) acc[ns] = z;

    for (int ks = 0; ks < 8; ++ks) {
        const float* ap = X + (size_t)(rw + lr) * C_ + ks * 32 + lg * 8;
        float4 a0 = *(const float4*)ap;
        float4 a1 = *(const float4*)(ap + 4);
        bf16x8 af;
        af[0] = (__bf16)a0.x; af[1] = (__bf16)a0.y; af[2] = (__bf16)a0.z; af[3] = (__bf16)a0.w;
        af[4] = (__bf16)a1.x; af[5] = (__bf16)a1.y; af[6] = (__bf16)a1.z; af[7] = (__bf16)a1.w;
#pragma unroll
        for (int ns = 0; ns < 16; ++ns) {
            bf16x8 bfv = *(const bf16x8*)(W + (size_t)(ns * 16 + lr) * C_ + ks * 32 + lg * 8);
            acc[ns] = __builtin_amdgcn_mfma_f32_16x16x32_bf16(af, bfv, acc[ns], 0, 0, 0);
        }
    }

    if (pz < 2) {
#pragma unroll
        for (int ns = 0; ns < 16; ++ns) {
            int j = ns * 16 + lr;
            float bj = bias[j];
            int h = j >> 5, d = j & 31;
#pragma unroll
            for (int reg = 0; reg < 4; ++reg) {
                int r = rw + lg * 4 + reg;
                int bb = r >> 11, n = r & (N_ - 1);
                float val = acc[ns][reg] + bj;
                if (pz == 0)
                    qb[(((size_t)bb * H_ + h) * N_ + n) * DH_ + d] = (__bf16)val;
                else
                    kb[(((size_t)bb * H_ + h) * M_ + n) * DH_ + d] = (__bf16)val;
            }
        }
    } else {
        // v^T: lane's 4 regs are 4 consecutive n for fixed d -> packed 8B writes
        int r = rw + lg * 4;
        int bb = r >> 11, n = r & (N_ - 1);
#pragma unroll
        for (int ns = 0; ns < 16; ++ns) {
            int j = ns * 16 + lr;
            float bj = bias[j];
            int h = j >> 5, d = j & 31;
            ushort4 pk;
            __bf16 t0 = (__bf16)(acc[ns][0] + bj);
            __bf16 t1 = (__bf16)(acc[ns][1] + bj);
            __bf16 t2 = (__bf16)(acc[ns][2] + bj);
            __bf16 t3 = (__bf16)(acc[ns][3] + bj);
            pk.x = __builtin_bit_cast(unsigned short, t0);
            pk.y = __builtin_bit_cast(unsigned short, t1);
            pk.z = __builtin_bit_cast(unsigned short, t2);
            pk.w = __builtin_bit_cast(unsigned short, t3);
            *(ushort4*)((unsigned short*)vt + (((size_t)bb * H_ + h) * DH_ + d) * M_ + n) = pk;
        }
    }
}

// ---------------- Kernel 2: fused LRPE flash attention (barrier-free loop) ---
// grid 512 linearized, block 512 (8 waves = 8 heads). Q-tile = 16 rows.
// Swapped QK^T: lane holds S^T[m][n=lr] -> lane-local softmax over m.
__global__ __launch_bounds__(512, 4) void attn_kernel(
    const __bf16* __restrict__ qb, const __bf16* __restrict__ kb,
    const __bf16* __restrict__ vt, const int* __restrict__ ridx,
    const float* __restrict__ kmask, const float* __restrict__ rbank,
    float* __restrict__ out)
{
    __shared__ __bf16 Pall[H_][16][R_];      // 32 KB: per-head q.rpe scores
    __shared__ unsigned int Pt[H_][512];     // 16 KB: per-wave P^T roundtrip (swizzled words)

    // XCD-aware swizzle: lin%8 -> XCD (heuristic); give each XCD one batch's K/V
    int lin = blockIdx.x;
    int b = (lin & 7) >> 1;
    int xq = ((lin >> 3) << 1) | (lin & 1);
    int n0 = xq * 16;

    int h = threadIdx.x >> 6, lane = threadIdx.x & 63;
    int lg = lane >> 4, lr = lane & 15;
    f32x4 z = {0.f, 0.f, 0.f, 0.f};

    // Q fragment: B-operand (col = n = lr, k = 8*lg..+8)
    bf16x8 qf = *(const bf16x8*)(qb + (((size_t)b * H_ + h) * N_ + n0 + lr) * DH_ + lg * 8);

    // P_all = Q @ rpe_h^T (16 x 128)
    for (int rs = 0; rs < R_ / 16; ++rs) {
        const float* rp = rbank + (size_t)(rs * 16 + lr) * C_ + h * DH_ + lg * 8;
        float4 r0v = *(const float4*)rp;
        float4 r1v = *(const float4*)(rp + 4);
        bf16x8 rf;
        rf[0] = (__bf16)r0v.x; rf[1] = (__bf16)r0v.y; rf[2] = (__bf16)r0v.z; rf[3] = (__bf16)r0v.w;
        rf[4] = (__bf16)r1v.x; rf[5] = (__bf16)r1v.y; rf[6] = (__bf16)r1v.z; rf[7] = (__bf16)r1v.w;
        f32x4 pc = __builtin_amdgcn_mfma_f32_16x16x32_bf16(qf, rf, z, 0, 0, 0);
#pragma unroll
        for (int reg = 0; reg < 4; ++reg)
            Pall[h][lg * 4 + reg][rs * 16 + lr] = (__bf16)pc[reg];
    }
    __syncthreads();   // only barrier in the kernel

    const float scale = 0.17677669529663687f; // 1/sqrt(32)
    const __bf16* Kh = kb + ((size_t)b * H_ + h) * M_ * DH_;
    const __bf16* Vh = vt + ((size_t)b * H_ + h) * DH_ * M_;
    const float* km = kmask + (size_t)b * M_;
    const int* ixr = ridx + ((size_t)b * N_ + n0 + lr) * M_ + 4 * lg;
    unsigned int* Ptw = &Pt[h][0];
    const __bf16* PallR = &Pall[h][lr][0];
    int swz = (lr & 7) << 2;

    float mrow = -1e30f, lrun = 0.f;
    f32x4 acc[2] = {z, z};

    int4 ixc[4];
#pragma unroll
    for (int ms = 0; ms < 4; ++ms) ixc[ms] = *(const int4*)(ixr + 16 * ms);

    for (int mt = 0; mt < M_ / 64; ++mt) {
        int m0 = mt * 64;

        // prefetch next tile's indices (registers; HBM latency hides under compute)
        int pm = (mt < 31) ? m0 + 64 : 0;
        int4 ixn[4];
#pragma unroll
        for (int ms = 0; ms < 4; ++ms) ixn[ms] = *(const int4*)(ixr + pm + 16 * ms);

        // K fragments (A-operand: row = m-local = lr, k = 8*lg..+8)
        bf16x8 kf[4];
#pragma unroll
        for (int ms = 0; ms < 4; ++ms)
            kf[ms] = *(const bf16x8*)(Kh + (size_t)(m0 + ms * 16 + lr) * DH_ + lg * 8);

        // RPE gather: this lane's rows are all n = lr, m = 16*ms + 4*lg + reg
        float pg[16];
#pragma unroll
        for (int ms = 0; ms < 4; ++ms) {
            pg[ms * 4 + 0] = (float)PallR[ixc[ms].x];
            pg[ms * 4 + 1] = (float)PallR[ixc[ms].y];
            pg[ms * 4 + 2] = (float)PallR[ixc[ms].z];
            pg[ms * 4 + 3] = (float)PallR[ixc[ms].w];
        }

        float4 mk[4];
#pragma unroll
        for (int ms = 0; ms < 4; ++ms)
            mk[ms] = *(const float4*)(km + m0 + ms * 16 + 4 * lg);

        // S^T = K @ Q^T : D[row=m][col=n=lr]
        f32x4 st[4];
#pragma unroll
        for (int ms = 0; ms < 4; ++ms)
            st[ms] = __builtin_amdgcn_mfma_f32_16x16x32_bf16(kf[ms], qf, z, 0, 0, 0);

        float sv[16];
#pragma unroll
        for (int ms = 0; ms < 4; ++ms) {
            sv[ms * 4 + 0] = (st[ms][0] + pg[ms * 4 + 0]) * scale + mk[ms].x;
            sv[ms * 4 + 1] = (st[ms][1] + pg[ms * 4 + 1]) * scale + mk[ms].y;
            sv[ms * 4 + 2] = (st[ms][2] + pg[ms * 4 + 2]) * scale + mk[ms].z;
            sv[ms * 4 + 3] = (st[ms][3] + pg[ms * 4 + 3]) * scale + mk[ms].w;
        }

        // row max over m: 15 lane-local + 2 shfl (lanes lr, lr+16, lr+32, lr+48 share row)
        float pmax = sv[0];
#pragma unroll
        for (int j = 1; j < 16; ++j) pmax = fmaxf(pmax, sv[j]);
        pmax = fmaxf(pmax, __shfl_xor(pmax, 16));
        pmax = fmaxf(pmax, __shfl_xor(pmax, 32));

        // defer-max: only rescale when some row's max grew by > 8
        if (!__all(pmax - mrow <= 8.0f)) {
            float mnew = fmaxf(mrow, pmax);
            float alpha = __expf(mrow - mnew);
            mrow = mnew;
            lrun *= alpha;
#pragma unroll
            for (int reg = 0; reg < 4; ++reg) {
                float aB = __shfl(alpha, lg * 4 + reg);  // row n=4lg+reg lives at lane n
                acc[0][reg] *= aB;
                acc[1][reg] *= aB;
            }
        }

        float pq[16], ssum = 0.f;
#pragma unroll
        for (int j = 0; j < 16; ++j) {
            pq[j] = __expf(sv[j] - mrow);
            ssum += pq[j];
        }
        ssum += __shfl_xor(ssum, 16);
        ssum += __shfl_xor(ssum, 32);
        lrun += ssum;

        // pack P^T pairs -> swizzled LDS words: word (m/2) of row n=lr
#pragma unroll
        for (int ms = 0; ms < 4; ++ms) {
#pragma unroll
            for (int j = 0; j < 2; ++j) {
                __bf16 lo = (__bf16)pq[ms * 4 + 2 * j];
                __bf16 hi = (__bf16)pq[ms * 4 + 2 * j + 1];
                unsigned int wv = (unsigned int)__builtin_bit_cast(unsigned short, lo) |
                                  ((unsigned int)__builtin_bit_cast(unsigned short, hi) << 16);
                Ptw[lr * 32 + ((ms * 8 + lg * 2 + j) ^ swz)] = wv;
            }
        }
        asm volatile("s_waitcnt lgkmcnt(0)" ::: "memory");

        // O += P @ V : A-frag rows n=lr from Pt, B-frag = V^T rows d
#pragma unroll
        for (int ks = 0; ks < 2; ++ks) {
            bf16x8 pf = *(const bf16x8*)(&Ptw[lr * 32 + ((ks * 16 + lg * 4) ^ swz)]);
#pragma unroll
            for (int ds = 0; ds < 2; ++ds) {
                bf16x8 vf = *(const bf16x8*)(Vh + (size_t)(ds * 16 + lr) * M_ + m0 + ks * 32 + lg * 8);
                acc[ds] = __builtin_amdgcn_mfma_f32_16x16x32_bf16(pf, vf, acc[ds], 0, 0, 0);
            }
        }

#pragma unroll
        for (int ms = 0; ms < 4; ++ms) ixc[ms] = ixn[ms];
    }

    // epilogue: out[b, n0+n, h*32 + d] = acc / lsum (rows n=4lg+reg; lsum lives at lane n)
#pragma unroll
    for (int reg = 0; reg < 4; ++reg) {
        float lB = __shfl(lrun, lg * 4 + reg);
        float inv = 1.0f / lB;
        size_t rb = ((size_t)b * N_ + n0 + lg * 4 + reg) * C_ + h * DH_;
        out[rb + lr] = acc[0][reg] * inv;
        out[rb + 16 + lr] = acc[1][reg] * inv;
    }
}

// ---------------- launch ----------------------------------------------------
extern "C" void kernel_launch(void* const* d_in, const int* in_sizes, int n_in,
                              void* d_out, int out_size, void* d_ws, size_t ws_size,
                              hipStream_t stream) {
    const float* Xq = (const float*)d_in[0];
    const float* Xk = (const float*)d_in[1];
    const float* Xv = (const float*)d_in[2];
    const int* ridx = (const int*)d_in[3];
    const float* kmask = (const float*)d_in[4];
    const float* Wq = (const float*)d_in[5];
    const float* bq = (const float*)d_in[6];
    const float* Wk = (const float*)d_in[7];
    const float* bk = (const float*)d_in[8];
    const float* Wv = (const float*)d_in[9];
    const float* bv = (const float*)d_in[10];
    const float* rbank = (const float*)d_in[11];
    float* outp = (float*)d_out;

    char* ws = (char*)d_ws;
    __bf16* Wt = (__bf16*)ws;                               // 393216 B
    __bf16* qb = (__bf16*)(ws + 393216);                    // 4 MB
    __bf16* kb = (__bf16*)(ws + 393216 + 4194304);          // 4 MB
    __bf16* vt = (__bf16*)(ws + 393216 + 8388608);          // 4 MB

    wtrans_kernel<<<dim3(8, 8, 3), dim3(32, 8), 0, stream>>>(Wq, Wk, Wv, Wt);
    proj_kernel<<<dim3(128, 1, 3), 256, 0, stream>>>(Xq, Xk, Xv, bq, bk, bv, Wt, qb, kb, vt);
    attn_kernel<<<512, 512, 0, stream>>>(qb, kb, vt, ridx, kmask, rbank, outp);
}

// Round 3
// 168.221 us; speedup vs baseline: 1.2531x; 1.2531x over previous
//
#include <hip/hip_runtime.h>
#include <hip/hip_bf16.h>

#define B_ 4
#define N_ 2048
#define M_ 2048
#define C_ 256
#define H_ 8
#define DH_ 32
#define R_ 128

typedef __bf16 bf16x8 __attribute__((ext_vector_type(8)));
typedef float f32x4 __attribute__((ext_vector_type(4)));

#define QSCL 0.25503486f      // (1/sqrt(32)) * log2(e)
#define LOG2E 1.4426950408889634f
#define DTHR 11.5f            // defer-max threshold in log2 domain (~8 nats)

#define GLOAD_LDS4(gp, lp)                                            \
    __builtin_amdgcn_global_load_lds(                                 \
        (const __attribute__((address_space(1))) void*)(gp),          \
        (__attribute__((address_space(3))) void*)(lp), 4, 0, 0)

// ---------------- Kernel 0: W^T (f32 -> bf16) for Wq, Wk, Wv ----------------
__global__ __launch_bounds__(256) void wtrans_kernel(
    const float* __restrict__ Wq, const float* __restrict__ Wk,
    const float* __restrict__ Wv, __bf16* __restrict__ out)
{
    __shared__ float t[32][33];
    int pz = blockIdx.z;
    const float* W = pz == 0 ? Wq : (pz == 1 ? Wk : Wv);
    int j0 = blockIdx.x * 32, k0 = blockIdx.y * 32;
    int tx = threadIdx.x, ty = threadIdx.y;
#pragma unroll
    for (int i = 0; i < 4; ++i)
        t[ty + 8 * i][tx] = W[(k0 + ty + 8 * i) * C_ + j0 + tx];
    __syncthreads();
    __bf16* o = out + (size_t)pz * C_ * C_;
#pragma unroll
    for (int i = 0; i < 4; ++i)
        o[(j0 + ty + 8 * i) * C_ + k0 + tx] = (__bf16)t[tx][ty + 8 * i];
}

// ---------------- Kernel 1: projections X@W+b -> bf16 ----------------------
// pz=0: q (B,H,N,Dh) scaled by QSCL; pz=1: k (B,H,M,Dh); pz=2: v^T (B,H,Dh,M)
// q/k use swapped-operand MFMA so each lane holds 4 consecutive d -> packed stores.
__global__ __launch_bounds__(256) void proj_kernel(
    const float* __restrict__ Xq, const float* __restrict__ Xk, const float* __restrict__ Xv,
    const float* __restrict__ bq, const float* __restrict__ bk, const float* __restrict__ bv,
    const __bf16* __restrict__ Wt,
    __bf16* __restrict__ qb, __bf16* __restrict__ kb, __bf16* __restrict__ vt)
{
    int pz = blockIdx.z;
    const float* X = pz == 0 ? Xq : (pz == 1 ? Xk : Xv);
    const float* bias = pz == 0 ? bq : (pz == 1 ? bk : bv);
    const __bf16* W = Wt + (size_t)pz * C_ * C_;

    int r0 = blockIdx.x * 64;
    int w = threadIdx.x >> 6, lane = threadIdx.x & 63;
    int lg = lane >> 4, lr = lane & 15;
    int rw = r0 + w * 16;

    f32x4 z = {0.f, 0.f, 0.f, 0.f};
    f32x4 acc[16];
#pragma unroll
    for (int ns = 0; ns < 16; ++ns) acc[ns] = z;

    for (int ks = 0; ks < 8; ++ks) {
        const float* ap = X + (size_t)(rw + lr) * C_ + ks * 32 + lg * 8;
        float4 a0 = *(const float4*)ap;
        float4 a1 = *(const float4*)(ap + 4);
        bf16x8 af;
        af[0] = (__bf16)a0.x; af[1] = (__bf16)a0.y; af[2] = (__bf16)a0.z; af[3] = (__bf16)a0.w;
        af[4] = (__bf16)a1.x; af[5] = (__bf16)a1.y; af[6] = (__bf16)a1.z; af[7] = (__bf16)a1.w;
        if (pz < 2) {
#pragma unroll
            for (int ns = 0; ns < 16; ++ns) {
                bf16x8 bfv = *(const bf16x8*)(W + (size_t)(ns * 16 + lr) * C_ + ks * 32 + lg * 8);
                acc[ns] = __builtin_amdgcn_mfma_f32_16x16x32_bf16(bfv, af, acc[ns], 0, 0, 0);
            }
        } else {
#pragma unroll
            for (int ns = 0; ns < 16; ++ns) {
                bf16x8 bfv = *(const bf16x8*)(W + (size_t)(ns * 16 + lr) * C_ + ks * 32 + lg * 8);
                acc[ns] = __builtin_amdgcn_mfma_f32_16x16x32_bf16(af, bfv, acc[ns], 0, 0, 0);
            }
        }
    }

    if (pz < 2) {
        // lane holds rows j = ns*16 + 4*lg + reg (4 consecutive d), col n = rw+lr
        int ng = rw + lr;
        int bb = ng >> 11, n = ng & (N_ - 1);
        unsigned short* dst = (unsigned short*)(pz == 0 ? qb : kb);
#pragma unroll
        for (int ns = 0; ns < 16; ++ns) {
            int j0b = ns * 16 + 4 * lg;
            float4 b4 = *(const float4*)(bias + j0b);
            int hh = j0b >> 5, d0 = j0b & 31;
            float v0 = acc[ns][0] + b4.x, v1 = acc[ns][1] + b4.y;
            float v2 = acc[ns][2] + b4.z, v3 = acc[ns][3] + b4.w;
            if (pz == 0) { v0 *= QSCL; v1 *= QSCL; v2 *= QSCL; v3 *= QSCL; }
            ushort4 pk;
            pk.x = __builtin_bit_cast(unsigned short, (__bf16)v0);
            pk.y = __builtin_bit_cast(unsigned short, (__bf16)v1);
            pk.z = __builtin_bit_cast(unsigned short, (__bf16)v2);
            pk.w = __builtin_bit_cast(unsigned short, (__bf16)v3);
            *(ushort4*)(dst + ((((size_t)bb * H_ + hh) * 2048 + n) * DH_ + d0)) = pk;
        }
    } else {
        // v^T: lane's 4 regs are 4 consecutive n for fixed d -> packed 8B writes
        int r = rw + lg * 4;
        int bb = r >> 11, n = r & (N_ - 1);
#pragma unroll
        for (int ns = 0; ns < 16; ++ns) {
            int j = ns * 16 + lr;
            float bj = bias[j];
            int hh = j >> 5, d = j & 31;
            ushort4 pk;
            pk.x = __builtin_bit_cast(unsigned short, (__bf16)(acc[ns][0] + bj));
            pk.y = __builtin_bit_cast(unsigned short, (__bf16)(acc[ns][1] + bj));
            pk.z = __builtin_bit_cast(unsigned short, (__bf16)(acc[ns][2] + bj));
            pk.w = __builtin_bit_cast(unsigned short, (__bf16)(acc[ns][3] + bj));
            *(ushort4*)((unsigned short*)vt + (((size_t)bb * H_ + hh) * DH_ + d) * M_ + n) = pk;
        }
    }
}

// ---------------- Kernel 2: fused LRPE flash attention ----------------------
// grid 512, block 512 (8 waves = 8 heads). Q pre-scaled by QSCL (log2 domain).
// idx double-buffered in LDS via async global_load_lds (swizzled both sides).
// P^T -> A-frag redistribution fully in-register (shfl), no LDS roundtrip.
__global__ __launch_bounds__(512) void attn_kernel(
    const __bf16* __restrict__ qb, const __bf16* __restrict__ kb,
    const __bf16* __restrict__ vt, const int* __restrict__ ridx,
    const float* __restrict__ kmask, const float* __restrict__ rbank,
    float* __restrict__ out)
{
    __shared__ __bf16 Pall[H_][16][R_];   // 32 KB (per-head, own-wave only)
    __shared__ int idxS[2][16 * 64];      // 8 KB, double-buffered, XOR-swizzled

    int lin = blockIdx.x;
    int b = (lin & 7) >> 1;                      // batch pinned to XCD pair (L2 K/V locality)
    int xq = ((lin >> 3) << 1) | (lin & 1);
    int n0 = xq * 16;

    int h = threadIdx.x >> 6, lane = threadIdx.x & 63;
    int lg = lane >> 4, lr = lane & 15;
    f32x4 z = {0.f, 0.f, 0.f, 0.f};

    const int* ixblk = ridx + ((size_t)b * N_ + n0) * M_;

    // ---- stage idx tile 0 (async) before Pall compute ----
#pragma unroll
    for (int i = 0; i < 2; ++i) {
        int r = 2 * h + i;
        int sw = 4 * (r & 7);
        GLOAD_LDS4(ixblk + (size_t)r * M_ + (lane ^ sw), &idxS[0][r * 64]);
    }

    // Q fragment (B-operand: col n = lr, k = 8*lg..+8); pre-scaled by QSCL
    bf16x8 qf = *(const bf16x8*)(qb + (((size_t)b * H_ + h) * N_ + n0 + lr) * DH_ + lg * 8);

    // P_all = Q @ rpe_h^T (16 x 128), own head only -> no barrier needed
    for (int rs = 0; rs < R_ / 16; ++rs) {
        const float* rp = rbank + (size_t)(rs * 16 + lr) * C_ + h * DH_ + lg * 8;
        float4 r0v = *(const float4*)rp;
        float4 r1v = *(const float4*)(rp + 4);
        bf16x8 rf;
        rf[0] = (__bf16)r0v.x; rf[1] = (__bf16)r0v.y; rf[2] = (__bf16)r0v.z; rf[3] = (__bf16)r0v.w;
        rf[4] = (__bf16)r1v.x; rf[5] = (__bf16)r1v.y; rf[6] = (__bf16)r1v.z; rf[7] = (__bf16)r1v.w;
        f32x4 pc = __builtin_amdgcn_mfma_f32_16x16x32_bf16(qf, rf, z, 0, 0, 0);
#pragma unroll
        for (int reg = 0; reg < 4; ++reg)
            Pall[h][lg * 4 + reg][rs * 16 + lr] = (__bf16)pc[reg];
    }

    __syncthreads();   // idx tile 0 landed (syncthreads drains vmcnt) + Pall visible

    const __bf16* Kh = kb + ((size_t)b * H_ + h) * M_ * DH_;
    const __bf16* Vh = vt + ((size_t)b * H_ + h) * DH_ * M_;
    const float* km = kmask + (size_t)b * M_;
    const __bf16* PallR = &Pall[h][lr][0];
    int swzR = 4 * (lr & 7);

    float mrow = -1e30f, lrun = 0.f;
    f32x4 acc[2] = {z, z};
    int cb = 0;

    for (int mt = 0; mt < M_ / 64; ++mt) {
        int m0 = mt * 64;
        int m0n = (mt < 31) ? m0 + 64 : m0;

        // (1) stage next idx tile into other buffer (async -> landed by end barrier)
#pragma unroll
        for (int i = 0; i < 2; ++i) {
            int r = 2 * h + i;
            int sw = 4 * (r & 7);
            GLOAD_LDS4(ixblk + (size_t)r * M_ + m0n + (lane ^ sw), &idxS[cb ^ 1][r * 64]);
        }

        // K / V / mask loads for this tile (consumed mid/late tile)
        bf16x8 kf[4];
#pragma unroll
        for (int ms = 0; ms < 4; ++ms)
            kf[ms] = *(const bf16x8*)(Kh + (size_t)(m0 + ms * 16 + lr) * DH_ + lg * 8);
        bf16x8 vf[4];
#pragma unroll
        for (int ds = 0; ds < 2; ++ds)
#pragma unroll
            for (int ks = 0; ks < 2; ++ks)
                vf[ds * 2 + ks] = *(const bf16x8*)(Vh + (size_t)(ds * 16 + lr) * M_ + m0 + ks * 32 + lg * 8);
        float4 mkv[4];
#pragma unroll
        for (int ms = 0; ms < 4; ++ms)
            mkv[ms] = *(const float4*)(km + m0 + ms * 16 + 4 * lg);

        // (2) idx (swizzled b128) + Pall gather
        int4 ixv[4];
#pragma unroll
        for (int ms = 0; ms < 4; ++ms)
            ixv[ms] = *(const int4*)&idxS[cb][lr * 64 + ((16 * ms + 4 * lg) ^ swzR)];
        float sv[16];
#pragma unroll
        for (int ms = 0; ms < 4; ++ms) {
            sv[ms * 4 + 0] = (float)PallR[ixv[ms].x];
            sv[ms * 4 + 1] = (float)PallR[ixv[ms].y];
            sv[ms * 4 + 2] = (float)PallR[ixv[ms].z];
            sv[ms * 4 + 3] = (float)PallR[ixv[ms].w];
        }

        // (3) S^T = K @ Q^T : D[row=m][col=n=lr]  (log2 domain: Q pre-scaled)
        f32x4 st[4];
#pragma unroll
        for (int ms = 0; ms < 4; ++ms)
            st[ms] = __builtin_amdgcn_mfma_f32_16x16x32_bf16(kf[ms], qf, z, 0, 0, 0);

#pragma unroll
        for (int ms = 0; ms < 4; ++ms) {
            sv[ms * 4 + 0] = fmaf(mkv[ms].x, LOG2E, st[ms][0] + sv[ms * 4 + 0]);
            sv[ms * 4 + 1] = fmaf(mkv[ms].y, LOG2E, st[ms][1] + sv[ms * 4 + 1]);
            sv[ms * 4 + 2] = fmaf(mkv[ms].z, LOG2E, st[ms][2] + sv[ms * 4 + 2]);
            sv[ms * 4 + 3] = fmaf(mkv[ms].w, LOG2E, st[ms][3] + sv[ms * 4 + 3]);
        }

        // (4) softmax: lane-local max over 16 m + 2 shfl across groups
        float pmax = sv[0];
#pragma unroll
        for (int j = 1; j < 16; ++j) pmax = fmaxf(pmax, sv[j]);
        pmax = fmaxf(pmax, __shfl_xor(pmax, 16));
        pmax = fmaxf(pmax, __shfl_xor(pmax, 32));

        if (!__all(pmax - mrow <= DTHR)) {
            float mnew = fmaxf(mrow, pmax);
            float alpha = exp2f(mrow - mnew);
            mrow = mnew;
            lrun *= alpha;
#pragma unroll
            for (int reg = 0; reg < 4; ++reg) {
                float aB = __shfl(alpha, lg * 4 + reg);
                acc[0][reg] *= aB;
                acc[1][reg] *= aB;
            }
        }

        float pq[16], ssum = 0.f;
#pragma unroll
        for (int j = 0; j < 16; ++j) {
            pq[j] = exp2f(sv[j] - mrow);
            ssum += pq[j];
        }
        ssum += __shfl_xor(ssum, 16);
        ssum += __shfl_xor(ssum, 32);
        lrun += ssum;

        // (5) pack P^T pairs; redistribute to A-frag layout via shfl (no LDS)
        unsigned int pw[8];
#pragma unroll
        for (int p = 0; p < 8; ++p) {
            unsigned int lo = __builtin_bit_cast(unsigned short, (__bf16)pq[2 * p]);
            unsigned int hi = __builtin_bit_cast(unsigned short, (__bf16)pq[2 * p + 1]);
            pw[p] = lo | (hi << 16);
        }
        bool hiHalf = lane >= 32;
#pragma unroll
        for (int ks = 0; ks < 2; ++ks) {
            uint4 wv;
            unsigned int* wp = (unsigned int*)&wv;
#pragma unroll
            for (int wi = 0; wi < 4; ++wi) {
                int src = (((2 * lg + (wi >> 1)) & 3) << 4) + lr;
                unsigned int a0 = __shfl(pw[4 * ks + (wi & 1)], src);
                unsigned int a1 = __shfl(pw[4 * ks + 2 + (wi & 1)], src);
                wp[wi] = hiHalf ? a1 : a0;
            }
            bf16x8 pf = __builtin_bit_cast(bf16x8, wv);
#pragma unroll
            for (int ds = 0; ds < 2; ++ds)
                acc[ds] = __builtin_amdgcn_mfma_f32_16x16x32_bf16(pf, vf[ds * 2 + ks], acc[ds], 0, 0, 0);
        }

        // (6) one barrier per tile; its vmcnt drain covers the idx stage
        __syncthreads();
        cb ^= 1;
    }

    // epilogue: out[b, n0+n, h*32+d] = acc / lsum  (row n stats live at lane n)
#pragma unroll
    for (int reg = 0; reg < 4; ++reg) {
        float lB = __shfl(lrun, lg * 4 + reg);
        float inv = 1.0f / lB;
        size_t rb = ((size_t)b * N_ + n0 + lg * 4 + reg) * C_ + h * DH_;
        out[rb + lr] = acc[0][reg] * inv;
        out[rb + 16 + lr] = acc[1][reg] * inv;
    }
}

// ---------------- launch ----------------------------------------------------
extern "C" void kernel_launch(void* const* d_in, const int* in_sizes, int n_in,
                              void* d_out, int out_size, void* d_ws, size_t ws_size,
                              hipStream_t stream) {
    const float* Xq = (const float*)d_in[0];
    const float* Xk = (const float*)d_in[1];
    const float* Xv = (const float*)d_in[2];
    const int* ridx = (const int*)d_in[3];
    const float* kmask = (const float*)d_in[4];
    const float* Wq = (const float*)d_in[5];
    const float* bq = (const float*)d_in[6];
    const float* Wk = (const float*)d_in[7];
    const float* bk = (const float*)d_in[8];
    const float* Wv = (const float*)d_in[9];
    const float* bv = (const float*)d_in[10];
    const float* rbank = (const float*)d_in[11];
    float* outp = (float*)d_out;

    char* ws = (char*)d_ws;
    __bf16* Wt = (__bf16*)ws;                               // 393216 B
    __bf16* qb = (__bf16*)(ws + 393216);                    // 4 MB
    __bf16* kb = (__bf16*)(ws + 393216 + 4194304);          // 4 MB
    __bf16* vt = (__bf16*)(ws + 393216 + 8388608);          // 4 MB

    wtrans_kernel<<<dim3(8, 8, 3), dim3(32, 8), 0, stream>>>(Wq, Wk, Wv, Wt);
    proj_kernel<<<dim3(128, 1, 3), 256, 0, stream>>>(Xq, Xk, Xv, bq, bk, bv, Wt, qb, kb, vt);
    attn_kernel<<<512, 512, 0, stream>>>(qb, kb, vt, ridx, kmask, rbank, outp);
}